// Round 10
// baseline (291.503 us; speedup 1.0000x reference)
//
#include <hip/hip_runtime.h>

// LightGCN: x0 = dropout(concat(user,item)); out = (x0 + A x0 + A^2 x0 + A^3 x0)/4
// R18: spmm reverted to R16 (asm-forced MLP REGRESSED: R17 dur 57.7 vs 52.7,
//   VGPR 56 not 96-128, occupancy 53->35%. Verdict across R11/R15/R17: gather
//   fill-side pins at 307MB/~53us ~= 5.7TB/s for random 128B lines at ANY
//   per-wave depth -> request/fabric-throughput ceiling. Spmm lever closed.)
//   Remaining pot: ~132us of preproc (bin+bsort+gaps). Change: dropout moved
//   OFF the critical chain — fused into the k_bsort launch (blocks [0,147)
//   bucket-sort on <=147 CUs; blocks [147,1319) dropout stream on the idle
//   ~110 CUs). k_pre becomes bin-only (586 blocks), shortening bin->bsort.
// fp16 intermediates (R9): gather granule 128B, working set 19.2MB.
// CSR build (R8/R16): two-level counting sort; single-pass register bsort.
// SpMM (R11/R15): wave = 8 adjacent rows, 8-lane group per row, 16-edge
// batch, 2-deep ev prefetch (compiler-scheduled — best measured 52.7us).

static constexpr int NU = 100000;
static constexpr int NI = 50000;
static constexpr int NN = NU + NI;       // 150000
static constexpr int D  = 64;
static constexpr int E  = 2400000;
static constexpr int XN = NN * D;        // 9,600,000
static constexpr int NUD = NU * D;       // 6,400,000 (div by 8)
static constexpr int NB = (NN + 1023) >> 10;   // 147 buckets
static constexpr int BPC = 24000;        // bucket staging cap (mean 16327, +59 sigma)
static constexpr int BIN_T = 256;
static constexpr int BIN_U = 16;
static constexpr int BIN_CHUNK = BIN_T * BIN_U;   // 4096
static constexpr int BGRID = (E + BIN_CHUNK - 1) / BIN_CHUNK;   // 586
static constexpr int DGRID = (XN / 8 + 1023) / 1024;            // 1172 (1024 thr)
static constexpr int RPT = 24;           // k_bsort records per thread (24*1024 >= BPC)

typedef _Float16 half_t;
typedef _Float16 half8 __attribute__((ext_vector_type(8)));

__device__ __forceinline__ unsigned rotl32(unsigned x, int r) {
    return (x << r) | (x >> (32 - r));
}

// Threefry-2x32, 20 rounds (jax_threefry_partitionable=True layout, verified R1).
__device__ __forceinline__ void threefry2x32(unsigned k0, unsigned k1,
                                             unsigned x0, unsigned x1,
                                             unsigned& o0, unsigned& o1) {
    unsigned ks2 = k0 ^ k1 ^ 0x1BD11BDAu;
    x0 += k0; x1 += k1;
#define TF_R(r) { x0 += x1; x1 = rotl32(x1, r); x1 ^= x0; }
    TF_R(13) TF_R(15) TF_R(26) TF_R(6)   x0 += k1;  x1 += ks2 + 1u;
    TF_R(17) TF_R(29) TF_R(16) TF_R(24)  x0 += ks2; x1 += k0 + 2u;
    TF_R(13) TF_R(15) TF_R(26) TF_R(6)   x0 += k0;  x1 += k1 + 3u;
    TF_R(17) TF_R(29) TF_R(16) TF_R(24)  x0 += k1;  x1 += ks2 + 4u;
    TF_R(13) TF_R(15) TF_R(26) TF_R(6)   x0 += ks2; x1 += k0 + 5u;
#undef TF_R
    o0 = x0; o1 = x1;
}

// Bin-only preproc: 4096 edges/block -> 147 buckets (bucket = row>>10).
// 16 edges/thread via int4/float4 vector loads; LDS-aggregated appends;
// block-private dense runs in stg.
__global__ void __launch_bounds__(BIN_T) k_pre(const int* __restrict__ rows,
                                               const int* __restrict__ cols,
                                               const float* __restrict__ vals,
                                               int2* __restrict__ stg,
                                               int* __restrict__ pcnt) {
    __shared__ int lcnt[NB];
    __shared__ int gbase[NB];
    int tid = threadIdx.x;
    for (int i = tid; i < NB; i += BIN_T) lcnt[i] = 0;
    __syncthreads();
    int base = blockIdx.x * BIN_CHUNK;
    int lp[BIN_U];          // (bucket<<13) | loff, or -1 for tail
    int2 rec[BIN_U];
    int4  r4[4], c4[4];
    float4 v4[4];
    #pragma unroll
    for (int u4 = 0; u4 < 4; ++u4) {
        int e0 = base + (u4 * BIN_T + tid) * 4;   // E%4==0: all-in or all-out
        if (e0 < E) {
            r4[u4] = *(const int4*)(rows + e0);
            c4[u4] = *(const int4*)(cols + e0);
            v4[u4] = *(const float4*)(vals + e0);
        }
    }
    #pragma unroll
    for (int u4 = 0; u4 < 4; ++u4) {
        int e0 = base + (u4 * BIN_T + tid) * 4;
        int rr[4] = {r4[u4].x, r4[u4].y, r4[u4].z, r4[u4].w};
        int cc[4] = {c4[u4].x, c4[u4].y, c4[u4].z, c4[u4].w};
        float vv[4] = {v4[u4].x, v4[u4].y, v4[u4].z, v4[u4].w};
        #pragma unroll
        for (int k = 0; k < 4; ++k) {
            int u = u4 * 4 + k;
            if (e0 < E) {
                unsigned q = min(__float2int_rn(vv[k] * 65536.f), 16383);
                int b = rr[k] >> 10;
                int loff = atomicAdd(&lcnt[b], 1);
                lp[u] = (b << 13) | loff;           // loff < 4096 < 8192
                rec[u] = make_int2((int)((q << 18) | (unsigned)cc[k]), rr[k]);
            } else {
                lp[u] = -1;
            }
        }
    }
    __syncthreads();
    for (int i = tid; i < NB; i += BIN_T)
        gbase[i] = atomicAdd(&pcnt[i * 16], lcnt[i]);   // 64B-padded counters
    __syncthreads();
    #pragma unroll
    for (int u = 0; u < BIN_U; ++u) {
        if (lp[u] >= 0) {
            int b = lp[u] >> 13;
            int pos = gbase[b] + (lp[u] & 8191);
            if (pos < BPC) stg[(size_t)b * BPC + pos] = rec[u];
        }
    }
}

// Fused: blocks [0, NB) = bucket sort (single pass, records in registers);
// blocks [NB, NB+DGRID) = dropout-init (8 elems/thread, 1024 threads).
// bsort occupies <=147 CUs (latency-bound); dropout streams on the rest.
__global__ void __launch_bounds__(1024) k_bsort(const int2* __restrict__ stg,
                                                const int* __restrict__ pcnt,
                                                int* __restrict__ rp,
                                                unsigned* __restrict__ ev,
                                                const float* __restrict__ ue,
                                                const float* __restrict__ ie,
                                                half_t* __restrict__ x0h) {
    __shared__ int cnt[1024];
    __shared__ int wsum[16];
    __shared__ int sbb;
    int t = threadIdx.x;
    if (blockIdx.x >= NB) {
        // ---- dropout-init: 8 contiguous elems/thread ----
        int j8 = (blockIdx.x - NB) * 1024 + t;
        if (j8 >= XN / 8) return;
        int j0 = j8 * 8;
        // NUD % 8 == 0 -> chunk never straddles the ue/ie boundary.
        const float* src = (j0 < NUD) ? (ue + j0) : (ie + (j0 - NUD));
        float4 f0 = *(const float4*)(src);
        float4 f1 = *(const float4*)(src + 4);
        float f[8] = {f0.x, f0.y, f0.z, f0.w, f1.x, f1.y, f1.z, f1.w};
        half8 st;
        #pragma unroll
        for (int k = 0; k < 8; ++k) {
            unsigned o0, o1;
            threefry2x32(0u, 42u, 0u, (unsigned)(j0 + k), o0, o1);
            unsigned bits = o0 ^ o1;
            float u = __uint_as_float((bits >> 9) | 0x3f800000u) - 1.0f;
            st[k] = (half_t)((u < 0.8f) ? f[k] * 1.25f : 0.0f);
        }
        *(half8*)(x0h + j0) = st;
        return;
    }
    // ---- bucket-sort body (one block per bucket) ----
    int b = blockIdx.x;
    cnt[t] = 0;
    if (t < 64) {
        // exclusive prefix over buckets < b (one wave, <=3 values/lane)
        int a = 0;
        for (int i = t; i < b; i += 64) a += pcnt[i * 16];
        #pragma unroll
        for (int d = 1; d < 64; d <<= 1) a += __shfl_xor(a, d);
        if (t == 0) sbb = a;
    }
    if (b == 0 && t == 0) rp[NN] = E;    // sentinel
    __syncthreads();
    int tot = min(pcnt[b * 16], BPC);
    int bb = sbb;
    const int2* s = stg + (size_t)b * BPC;
    // Batched register load of this thread's records (independent loads).
    int2 rec[RPT];
    #pragma unroll
    for (int u = 0; u < RPT; ++u) {
        int i = t + u * 1024;
        if (i < tot) rec[u] = s[i];
    }
    #pragma unroll
    for (int u = 0; u < RPT; ++u) {
        int i = t + u * 1024;
        if (i < tot) atomicAdd(&cnt[rec[u].y & 1023], 1);
    }
    __syncthreads();
    // Block-wide exclusive scan of cnt[1024].
    int v = cnt[t];
    int lane = t & 63, w = t >> 6;
    int x = v;
    #pragma unroll
    for (int d = 1; d < 64; d <<= 1) {
        int y = __shfl_up(x, d);
        if (lane >= d) x += y;
    }
    if (lane == 63) wsum[w] = x;
    __syncthreads();
    if (w == 0 && lane < 16) {
        int sv = wsum[lane];
        #pragma unroll
        for (int d = 1; d < 16; d <<= 1) {
            int y = __shfl_up(sv, d);
            if (lane >= d) sv += y;
        }
        wsum[lane] = sv;
    }
    __syncthreads();
    int excl = ((w > 0) ? wsum[w - 1] : 0) + x - v;
    int row = (b << 10) + t;
    if (row < NN) rp[row] = bb + excl;
    __syncthreads();
    cnt[t] = bb + excl;               // becomes the scatter cursor
    __syncthreads();
    #pragma unroll
    for (int u = 0; u < RPT; ++u) {
        int i = t + u * 1024;
        if (i < tot) {
            int pos = atomicAdd(&cnt[rec[u].y & 1023], 1);
            ev[pos] = (unsigned)rec[u].x;
        }
    }
}

// Pull SpMM over exact CSR, fp16 x (R15/R16 version — 52.7us measured floor).
// Wave = 8 adjacent rows; 8-lane group owns a row (lane l = dims [8l,8l+8)).
// 16-edge batch, 2-deep ev prefetch, compiler-scheduled gathers.
// MODE 0: yh = A*xh (fp16 out). MODE 1: out_f32 = (x0h + y1h + xh + A*xh)*0.25.
template <int MODE>
__global__ void __launch_bounds__(256) k_spmm(const int* __restrict__ rp,
                                              const unsigned* __restrict__ ev,
                                              const half_t* __restrict__ xh,
                                              half_t* __restrict__ yh,
                                              const half_t* __restrict__ x0h,
                                              const half_t* __restrict__ y1h,
                                              float* __restrict__ out) {
    int wid  = threadIdx.x >> 6;             // wave in block: 0..3
    int lane = threadIdx.x & 63;
    int g    = lane >> 3;                    // group (row slot) 0..7
    int l    = lane & 7;                     // lane in group: dims [8l, 8l+8)
    int row  = blockIdx.x * 32 + wid * 8 + g;
    if (row >= NN) return;
    const float inv = 1.0f / 65536.0f;
    int s0  = rp[row];
    int cnt = rp[row + 1] - s0;
    float acc[8] = {0.f, 0.f, 0.f, 0.f, 0.f, 0.f, 0.f, 0.f};
    int gl = g << 3;                         // group's base lane
    int pc0 = (l < cnt)     ? (int)ev[s0 + l] : 0;
    int pc1 = (8 + l < cnt) ? (int)ev[s0 + 8 + l] : 0;
    for (int base = 0; base < cnt; base += 16) {
        int n0 = base + 16 + l;
        int n1 = base + 24 + l;
        int pn0 = (n0 < cnt) ? (int)ev[s0 + n0] : 0;   // prefetch next batch
        int pn1 = (n1 < cnt) ? (int)ev[s0 + n1] : 0;
        int pj[16];
        #pragma unroll
        for (int j = 0; j < 8; ++j) {
            pj[j]     = __shfl(pc0, gl | j);
            pj[8 + j] = __shfl(pc1, gl | j);
        }
        half8 xv[16];
        #pragma unroll
        for (int j = 0; j < 16; ++j)
            xv[j] = *(const half8*)(xh + (pj[j] & 0x3FFFF) * 64 + l * 8);  // 16B
        #pragma unroll
        for (int j = 0; j < 16; ++j) {
            float vj = (float)((unsigned)pj[j] >> 18) * inv;
            #pragma unroll
            for (int k = 0; k < 8; ++k)
                acc[k] = fmaf(vj, (float)xv[j][k], acc[k]);
        }
        pc0 = pn0;
        pc1 = pn1;
    }
    int o = row * 64 + l * 8;
    if (MODE == 0) {
        half8 st;
        #pragma unroll
        for (int k = 0; k < 8; ++k) st[k] = (half_t)acc[k];
        *(half8*)(yh + o) = st;
    } else {
        const half8 a0 = *(const half8*)(x0h + o);   // X0 (fp16)
        const half8 a1 = *(const half8*)(y1h + o);   // Y1 (fp16)
        const half8 a2 = *(const half8*)(xh + o);    // Y2 (linear read)
        float r[8];
        #pragma unroll
        for (int k = 0; k < 8; ++k)
            r[k] = ((float)a0[k] + (float)a1[k] + (float)a2[k] + acc[k]) * 0.25f;
        *(float4*)(out + o)     = make_float4(r[0], r[1], r[2], r[3]);
        *(float4*)(out + o + 4) = make_float4(r[4], r[5], r[6], r[7]);
    }
}

extern "C" void kernel_launch(void* const* d_in, const int* in_sizes, int n_in,
                              void* d_out, int out_size, void* d_ws, size_t ws_size,
                              hipStream_t stream) {
    const float* ue   = (const float*)d_in[0];
    const float* ie   = (const float*)d_in[1];
    const int*   rows = (const int*)d_in[2];
    const int*   cols = (const int*)d_in[3];
    const float* vals = (const float*)d_in[4];
    float* out = (float*)d_out;

    // Workspace: X0h [XN fp16 = 19.2MB] | Y1h [19.2MB] | Y2h [19.2MB]
    //   (stg aliases Y1h..Y2h: NB*BPC*8B = 28.2MB < 38.4MB, dead before spmm
    //    layer 1 writes Y1h) | ev [E*4 = 9.6MB] | rp [NN+1] | pcnt [NB*16].
    //   Total ~68 MB.
    half_t*   X0h   = (half_t*)d_ws;
    half_t*   Y1h   = X0h + XN;
    half_t*   Y2h   = Y1h + XN;
    int2*     stg   = (int2*)Y1h;
    unsigned* ev    = (unsigned*)(Y2h + XN);
    int*      rp    = (int*)(ev + E);
    int*      pcnt  = rp + NN + 4;

    (void)hipMemsetAsync(pcnt, 0, NB * 16 * sizeof(int), stream);
    k_pre<<<BGRID, BIN_T, 0, stream>>>(rows, cols, vals, stg, pcnt);
    k_bsort<<<NB + DGRID, 1024, 0, stream>>>(stg, pcnt, rp, ev, ue, ie, X0h);

    int sgrid = (NN + 31) / 32;   // 32 rows per block (4 waves x 8 rows)
    k_spmm<0><<<sgrid, 256, 0, stream>>>(rp, ev, X0h, Y1h, nullptr, nullptr, nullptr); // Y1=A*X0
    k_spmm<0><<<sgrid, 256, 0, stream>>>(rp, ev, Y1h, Y2h, nullptr, nullptr, nullptr); // Y2=A*Y1
    k_spmm<1><<<sgrid, 256, 0, stream>>>(rp, ev, Y2h, nullptr, X0h, Y1h, out);         // combine
}

// Round 11
// 283.032 us; speedup vs baseline: 1.0299x; 1.0299x over previous
//
#include <hip/hip_runtime.h>

// LightGCN: x0 = dropout(concat(user,item)); out = (x0 + A x0 + A^2 x0 + A^3 x0)/4
// R19: coalesce the two preproc scatters through LDS.
//   R18 neutral -> preproc cost is inside the kernels. Model: both bin and
//   bsort pay ~2M scattered-store L2 transactions (bin: 64 lanes x 8B to ~52
//   lines per wave-store; bsort: 16.3k random 4B stores/block) ~= 25+15us of
//   transaction cost vs a ~21us BW floor for all of preproc.
//   (a) k_pre: block-local sorted layout built in LDS (scan lcnt->lbase,
//       scatter recs+bucket-ids to LDS), then copy out with consecutive lanes
//       -> consecutive addresses (runs contiguous in LDS AND global).
//   (b) k_bsort: scatter into LDS sev[BPC] with bucket-LOCAL cursors, then
//       stream sev -> ev[bb..bb+tot) fully coalesced. LDS 100KB, 1 block/CU
//       (unchanged). Intra-row ev order changes -> summation order changes;
//       absmax may move slightly (<< threshold).
// SpMM (R11/R15, closed at ~52.7us: fill-side ~5.7TB/s ceiling for random
// 128B lines — R15/R17 both proved deeper per-wave MLP doesn't help).
// fp16 intermediates (R9). Two-level counting sort (R8/R16). Dropout fused
// in bsort launch (R18).

static constexpr int NU = 100000;
static constexpr int NI = 50000;
static constexpr int NN = NU + NI;       // 150000
static constexpr int D  = 64;
static constexpr int E  = 2400000;
static constexpr int XN = NN * D;        // 9,600,000
static constexpr int NUD = NU * D;       // 6,400,000 (div by 8)
static constexpr int NB = (NN + 1023) >> 10;   // 147 buckets
static constexpr int BPC = 24000;        // bucket staging cap (mean 16327, +59 sigma)
static constexpr int BIN_T = 256;
static constexpr int BIN_U = 16;
static constexpr int BIN_CHUNK = BIN_T * BIN_U;   // 4096
static constexpr int BGRID = (E + BIN_CHUNK - 1) / BIN_CHUNK;   // 586
static constexpr int DGRID = (XN / 8 + 1023) / 1024;            // 1172 (1024 thr)
static constexpr int RPT = 24;           // k_bsort records per thread (24*1024 >= BPC)

typedef _Float16 half_t;
typedef _Float16 half8 __attribute__((ext_vector_type(8)));

__device__ __forceinline__ unsigned rotl32(unsigned x, int r) {
    return (x << r) | (x >> (32 - r));
}

// Threefry-2x32, 20 rounds (jax_threefry_partitionable=True layout, verified R1).
__device__ __forceinline__ void threefry2x32(unsigned k0, unsigned k1,
                                             unsigned x0, unsigned x1,
                                             unsigned& o0, unsigned& o1) {
    unsigned ks2 = k0 ^ k1 ^ 0x1BD11BDAu;
    x0 += k0; x1 += k1;
#define TF_R(r) { x0 += x1; x1 = rotl32(x1, r); x1 ^= x0; }
    TF_R(13) TF_R(15) TF_R(26) TF_R(6)   x0 += k1;  x1 += ks2 + 1u;
    TF_R(17) TF_R(29) TF_R(16) TF_R(24)  x0 += ks2; x1 += k0 + 2u;
    TF_R(13) TF_R(15) TF_R(26) TF_R(6)   x0 += k0;  x1 += k1 + 3u;
    TF_R(17) TF_R(29) TF_R(16) TF_R(24)  x0 += k1;  x1 += ks2 + 4u;
    TF_R(13) TF_R(15) TF_R(26) TF_R(6)   x0 += ks2; x1 += k0 + 5u;
#undef TF_R
    o0 = x0; o1 = x1;
}

// Bin-only preproc: 4096 edges/block -> 147 buckets (bucket = row>>10).
// Records assembled block-locally-SORTED in LDS, then written out coalesced
// (consecutive lanes -> consecutive global addresses within each bucket run).
__global__ void __launch_bounds__(BIN_T) k_pre(const int* __restrict__ rows,
                                               const int* __restrict__ cols,
                                               const float* __restrict__ vals,
                                               int2* __restrict__ stg,
                                               int* __restrict__ pcnt) {
    __shared__ int lcnt[NB];
    __shared__ int lbase[NB];
    __shared__ int gbase[NB];
    __shared__ int2 lrec[BIN_CHUNK];            // 32 KB
    __shared__ unsigned char lbkt[BIN_CHUNK];   // 4 KB
    int tid = threadIdx.x;
    for (int i = tid; i < NB; i += BIN_T) lcnt[i] = 0;
    __syncthreads();
    int base = blockIdx.x * BIN_CHUNK;
    int nv = min(BIN_CHUNK, E - base);          // valid edges in this block
    int lp[BIN_U];          // (bucket<<13) | loff, or -1 for tail
    int2 rec[BIN_U];
    int4  r4[4], c4[4];
    float4 v4[4];
    #pragma unroll
    for (int u4 = 0; u4 < 4; ++u4) {
        int e0 = base + (u4 * BIN_T + tid) * 4;   // E%4==0: all-in or all-out
        if (e0 < E) {
            r4[u4] = *(const int4*)(rows + e0);
            c4[u4] = *(const int4*)(cols + e0);
            v4[u4] = *(const float4*)(vals + e0);
        }
    }
    #pragma unroll
    for (int u4 = 0; u4 < 4; ++u4) {
        int e0 = base + (u4 * BIN_T + tid) * 4;
        int rr[4] = {r4[u4].x, r4[u4].y, r4[u4].z, r4[u4].w};
        int cc[4] = {c4[u4].x, c4[u4].y, c4[u4].z, c4[u4].w};
        float vv[4] = {v4[u4].x, v4[u4].y, v4[u4].z, v4[u4].w};
        #pragma unroll
        for (int k = 0; k < 4; ++k) {
            int u = u4 * 4 + k;
            if (e0 < E) {
                unsigned q = min(__float2int_rn(vv[k] * 65536.f), 16383);
                int b = rr[k] >> 10;
                int loff = atomicAdd(&lcnt[b], 1);
                lp[u] = (b << 13) | loff;           // loff < 4096 < 8192
                rec[u] = make_int2((int)((q << 18) | (unsigned)cc[k]), rr[k]);
            } else {
                lp[u] = -1;
            }
        }
    }
    __syncthreads();
    // Exclusive scan lcnt -> lbase (wave 0), and global base atomics (all).
    if (tid < 64) {
        int carry = 0;
        for (int bb = 0; bb < NB; bb += 64) {
            int i = bb + tid;
            int v = (i < NB) ? lcnt[i] : 0;
            int x = v;
            #pragma unroll
            for (int d = 1; d < 64; d <<= 1) {
                int y = __shfl_up(x, d);
                if (tid >= d) x += y;
            }
            if (i < NB) lbase[i] = carry + x - v;
            carry += __shfl(x, 63);
        }
    }
    for (int i = tid; i < NB; i += BIN_T)
        gbase[i] = atomicAdd(&pcnt[i * 16], lcnt[i]);   // 64B-padded counters
    __syncthreads();
    // Scatter records into the block-local sorted LDS layout.
    #pragma unroll
    for (int u = 0; u < BIN_U; ++u) {
        if (lp[u] >= 0) {
            int b = lp[u] >> 13;
            int j = lbase[b] + (lp[u] & 8191);
            lrec[j] = rec[u];
            lbkt[j] = (unsigned char)b;
        }
    }
    __syncthreads();
    // Coalesced copy-out: consecutive lanes -> consecutive addresses.
    for (int j = tid; j < nv; j += BIN_T) {
        int b = lbkt[j];
        int pos = gbase[b] + (j - lbase[b]);
        if (pos < BPC) stg[(size_t)b * BPC + pos] = lrec[j];
    }
}

// Fused: blocks [0, NB) = bucket sort; blocks [NB, NB+DGRID) = dropout-init.
// Bucket sort: single pass (records in registers), sorted ev built in LDS
// with bucket-local cursors, then streamed out coalesced.
__global__ void __launch_bounds__(1024) k_bsort(const int2* __restrict__ stg,
                                                const int* __restrict__ pcnt,
                                                int* __restrict__ rp,
                                                unsigned* __restrict__ ev,
                                                const float* __restrict__ ue,
                                                const float* __restrict__ ie,
                                                half_t* __restrict__ x0h) {
    __shared__ int cnt[1024];
    __shared__ int wsum[16];
    __shared__ int sbb;
    __shared__ unsigned sev[BPC];    // 96 KB sorted-ev staging
    int t = threadIdx.x;
    if (blockIdx.x >= NB) {
        // ---- dropout-init: 8 contiguous elems/thread ----
        int j8 = (blockIdx.x - NB) * 1024 + t;
        if (j8 >= XN / 8) return;
        int j0 = j8 * 8;
        // NUD % 8 == 0 -> chunk never straddles the ue/ie boundary.
        const float* src = (j0 < NUD) ? (ue + j0) : (ie + (j0 - NUD));
        float4 f0 = *(const float4*)(src);
        float4 f1 = *(const float4*)(src + 4);
        float f[8] = {f0.x, f0.y, f0.z, f0.w, f1.x, f1.y, f1.z, f1.w};
        half8 st;
        #pragma unroll
        for (int k = 0; k < 8; ++k) {
            unsigned o0, o1;
            threefry2x32(0u, 42u, 0u, (unsigned)(j0 + k), o0, o1);
            unsigned bits = o0 ^ o1;
            float u = __uint_as_float((bits >> 9) | 0x3f800000u) - 1.0f;
            st[k] = (half_t)((u < 0.8f) ? f[k] * 1.25f : 0.0f);
        }
        *(half8*)(x0h + j0) = st;
        return;
    }
    // ---- bucket-sort body (one block per bucket) ----
    int b = blockIdx.x;
    cnt[t] = 0;
    if (t < 64) {
        // exclusive prefix over buckets < b (one wave, <=3 values/lane)
        int a = 0;
        for (int i = t; i < b; i += 64) a += pcnt[i * 16];
        #pragma unroll
        for (int d = 1; d < 64; d <<= 1) a += __shfl_xor(a, d);
        if (t == 0) sbb = a;
    }
    if (b == 0 && t == 0) rp[NN] = E;    // sentinel
    __syncthreads();
    int tot = min(pcnt[b * 16], BPC);
    int bb = sbb;
    const int2* s = stg + (size_t)b * BPC;
    // Batched register load of this thread's records (independent loads).
    int2 rec[RPT];
    #pragma unroll
    for (int u = 0; u < RPT; ++u) {
        int i = t + u * 1024;
        if (i < tot) rec[u] = s[i];
    }
    #pragma unroll
    for (int u = 0; u < RPT; ++u) {
        int i = t + u * 1024;
        if (i < tot) atomicAdd(&cnt[rec[u].y & 1023], 1);
    }
    __syncthreads();
    // Block-wide exclusive scan of cnt[1024].
    int v = cnt[t];
    int lane = t & 63, w = t >> 6;
    int x = v;
    #pragma unroll
    for (int d = 1; d < 64; d <<= 1) {
        int y = __shfl_up(x, d);
        if (lane >= d) x += y;
    }
    if (lane == 63) wsum[w] = x;
    __syncthreads();
    if (w == 0 && lane < 16) {
        int sv = wsum[lane];
        #pragma unroll
        for (int d = 1; d < 16; d <<= 1) {
            int y = __shfl_up(sv, d);
            if (lane >= d) sv += y;
        }
        wsum[lane] = sv;
    }
    __syncthreads();
    int excl = ((w > 0) ? wsum[w - 1] : 0) + x - v;
    int row = (b << 10) + t;
    if (row < NN) rp[row] = bb + excl;
    __syncthreads();
    cnt[t] = excl;                    // bucket-LOCAL scatter cursor (into sev)
    __syncthreads();
    #pragma unroll
    for (int u = 0; u < RPT; ++u) {
        int i = t + u * 1024;
        if (i < tot) {
            int pos = atomicAdd(&cnt[rec[u].y & 1023], 1);
            sev[pos] = (unsigned)rec[u].x;
        }
    }
    __syncthreads();
    // Coalesced stream-out of the sorted bucket segment.
    for (int i = t; i < tot; i += 1024)
        ev[bb + i] = sev[i];
}

// Pull SpMM over exact CSR, fp16 x (R15/R16 version — 52.7us measured floor).
// Wave = 8 adjacent rows; 8-lane group owns a row (lane l = dims [8l,8l+8)).
// 16-edge batch, 2-deep ev prefetch, compiler-scheduled gathers.
// MODE 0: yh = A*xh (fp16 out). MODE 1: out_f32 = (x0h + y1h + xh + A*xh)*0.25.
template <int MODE>
__global__ void __launch_bounds__(256) k_spmm(const int* __restrict__ rp,
                                              const unsigned* __restrict__ ev,
                                              const half_t* __restrict__ xh,
                                              half_t* __restrict__ yh,
                                              const half_t* __restrict__ x0h,
                                              const half_t* __restrict__ y1h,
                                              float* __restrict__ out) {
    int wid  = threadIdx.x >> 6;             // wave in block: 0..3
    int lane = threadIdx.x & 63;
    int g    = lane >> 3;                    // group (row slot) 0..7
    int l    = lane & 7;                     // lane in group: dims [8l, 8l+8)
    int row  = blockIdx.x * 32 + wid * 8 + g;
    if (row >= NN) return;
    const float inv = 1.0f / 65536.0f;
    int s0  = rp[row];
    int cnt = rp[row + 1] - s0;
    float acc[8] = {0.f, 0.f, 0.f, 0.f, 0.f, 0.f, 0.f, 0.f};
    int gl = g << 3;                         // group's base lane
    int pc0 = (l < cnt)     ? (int)ev[s0 + l] : 0;
    int pc1 = (8 + l < cnt) ? (int)ev[s0 + 8 + l] : 0;
    for (int base = 0; base < cnt; base += 16) {
        int n0 = base + 16 + l;
        int n1 = base + 24 + l;
        int pn0 = (n0 < cnt) ? (int)ev[s0 + n0] : 0;   // prefetch next batch
        int pn1 = (n1 < cnt) ? (int)ev[s0 + n1] : 0;
        int pj[16];
        #pragma unroll
        for (int j = 0; j < 8; ++j) {
            pj[j]     = __shfl(pc0, gl | j);
            pj[8 + j] = __shfl(pc1, gl | j);
        }
        half8 xv[16];
        #pragma unroll
        for (int j = 0; j < 16; ++j)
            xv[j] = *(const half8*)(xh + (pj[j] & 0x3FFFF) * 64 + l * 8);  // 16B
        #pragma unroll
        for (int j = 0; j < 16; ++j) {
            float vj = (float)((unsigned)pj[j] >> 18) * inv;
            #pragma unroll
            for (int k = 0; k < 8; ++k)
                acc[k] = fmaf(vj, (float)xv[j][k], acc[k]);
        }
        pc0 = pn0;
        pc1 = pn1;
    }
    int o = row * 64 + l * 8;
    if (MODE == 0) {
        half8 st;
        #pragma unroll
        for (int k = 0; k < 8; ++k) st[k] = (half_t)acc[k];
        *(half8*)(yh + o) = st;
    } else {
        const half8 a0 = *(const half8*)(x0h + o);   // X0 (fp16)
        const half8 a1 = *(const half8*)(y1h + o);   // Y1 (fp16)
        const half8 a2 = *(const half8*)(xh + o);    // Y2 (linear read)
        float r[8];
        #pragma unroll
        for (int k = 0; k < 8; ++k)
            r[k] = ((float)a0[k] + (float)a1[k] + (float)a2[k] + acc[k]) * 0.25f;
        *(float4*)(out + o)     = make_float4(r[0], r[1], r[2], r[3]);
        *(float4*)(out + o + 4) = make_float4(r[4], r[5], r[6], r[7]);
    }
}

extern "C" void kernel_launch(void* const* d_in, const int* in_sizes, int n_in,
                              void* d_out, int out_size, void* d_ws, size_t ws_size,
                              hipStream_t stream) {
    const float* ue   = (const float*)d_in[0];
    const float* ie   = (const float*)d_in[1];
    const int*   rows = (const int*)d_in[2];
    const int*   cols = (const int*)d_in[3];
    const float* vals = (const float*)d_in[4];
    float* out = (float*)d_out;

    // Workspace: X0h [XN fp16 = 19.2MB] | Y1h [19.2MB] | Y2h [19.2MB]
    //   (stg aliases Y1h..Y2h: NB*BPC*8B = 28.2MB < 38.4MB, dead before spmm
    //    layer 1 writes Y1h) | ev [E*4 = 9.6MB] | rp [NN+1] | pcnt [NB*16].
    //   Total ~68 MB.
    half_t*   X0h   = (half_t*)d_ws;
    half_t*   Y1h   = X0h + XN;
    half_t*   Y2h   = Y1h + XN;
    int2*     stg   = (int2*)Y1h;
    unsigned* ev    = (unsigned*)(Y2h + XN);
    int*      rp    = (int*)(ev + E);
    int*      pcnt  = rp + NN + 4;

    (void)hipMemsetAsync(pcnt, 0, NB * 16 * sizeof(int), stream);
    k_pre<<<BGRID, BIN_T, 0, stream>>>(rows, cols, vals, stg, pcnt);
    k_bsort<<<NB + DGRID, 1024, 0, stream>>>(stg, pcnt, rp, ev, ue, ie, X0h);

    int sgrid = (NN + 31) / 32;   // 32 rows per block (4 waves x 8 rows)
    k_spmm<0><<<sgrid, 256, 0, stream>>>(rp, ev, X0h, Y1h, nullptr, nullptr, nullptr); // Y1=A*X0
    k_spmm<0><<<sgrid, 256, 0, stream>>>(rp, ev, Y1h, Y2h, nullptr, nullptr, nullptr); // Y2=A*Y1
    k_spmm<1><<<sgrid, 256, 0, stream>>>(rp, ev, Y2h, nullptr, X0h, Y1h, out);         // combine
}

// Round 12
// 275.846 us; speedup vs baseline: 1.0568x; 1.0261x over previous
//
#include <hip/hip_runtime.h>

// LightGCN: x0 = dropout(concat(user,item)); out = (x0 + A x0 + A^2 x0 + A^3 x0)/4
// R20: dropout moved back into the k_pre launch (R16 arrangement).
//   R19 post-mortem: only -8.5us of the predicted -20-30. Found culprit in
//   R18's fusion: k_bsort's static ~100KB LDS (sev) is reserved by EVERY
//   block including the 1172 dropout blocks -> dropout ran 1 block/CU,
//   serialized after the 147 sort blocks. Dropout is VALU-bound (threefry
//   ~110 ops/elem x 9.6M = ~13us chip floor at full occupancy) -> it was
//   costing ~20-25us serial. k_pre uses ~37KB at 256T -> 4 blocks/CU, so
//   dropout backfills bin at near-full occupancy there. k_bsort is now pure
//   bucket-sort (147 blocks).
// R19 (kept): both preproc scatters coalesced through LDS.
// SpMM (R11/R15, closed at ~52.7us: fill-side ~5.7TB/s ceiling for random
// 128B lines; R15/R17 proved deeper per-wave MLP doesn't help).
// fp16 intermediates (R9). Two-level counting sort (R8/R16).

static constexpr int NU = 100000;
static constexpr int NI = 50000;
static constexpr int NN = NU + NI;       // 150000
static constexpr int D  = 64;
static constexpr int E  = 2400000;
static constexpr int XN = NN * D;        // 9,600,000
static constexpr int NUD = NU * D;       // 6,400,000 (div by 8)
static constexpr int NB = (NN + 1023) >> 10;   // 147 buckets
static constexpr int BPC = 24000;        // bucket staging cap (mean 16327, +59 sigma)
static constexpr int BIN_T = 256;
static constexpr int BIN_U = 16;
static constexpr int BIN_CHUNK = BIN_T * BIN_U;   // 4096
static constexpr int BGRID = (E + BIN_CHUNK - 1) / BIN_CHUNK;   // 586
static constexpr int DGRID = (XN / 8 + BIN_T - 1) / BIN_T;      // 4688
static constexpr int RPT = 24;           // k_bsort records per thread (24*1024 >= BPC)

typedef _Float16 half_t;
typedef _Float16 half8 __attribute__((ext_vector_type(8)));

__device__ __forceinline__ unsigned rotl32(unsigned x, int r) {
    return (x << r) | (x >> (32 - r));
}

// Threefry-2x32, 20 rounds (jax_threefry_partitionable=True layout, verified R1).
__device__ __forceinline__ void threefry2x32(unsigned k0, unsigned k1,
                                             unsigned x0, unsigned x1,
                                             unsigned& o0, unsigned& o1) {
    unsigned ks2 = k0 ^ k1 ^ 0x1BD11BDAu;
    x0 += k0; x1 += k1;
#define TF_R(r) { x0 += x1; x1 = rotl32(x1, r); x1 ^= x0; }
    TF_R(13) TF_R(15) TF_R(26) TF_R(6)   x0 += k1;  x1 += ks2 + 1u;
    TF_R(17) TF_R(29) TF_R(16) TF_R(24)  x0 += ks2; x1 += k0 + 2u;
    TF_R(13) TF_R(15) TF_R(26) TF_R(6)   x0 += k0;  x1 += k1 + 3u;
    TF_R(17) TF_R(29) TF_R(16) TF_R(24)  x0 += k1;  x1 += ks2 + 4u;
    TF_R(13) TF_R(15) TF_R(26) TF_R(6)   x0 += ks2; x1 += k0 + 5u;
#undef TF_R
    o0 = x0; o1 = x1;
}

// Fused: blocks [0, BGRID) = edge binning (LDS-sorted, coalesced copy-out);
// blocks [BGRID, BGRID+DGRID) = dropout-init (8 elems/thread, 256 threads,
// ~37KB LDS reservation -> 4 blocks/CU backfill behind the bin blocks).
__global__ void __launch_bounds__(BIN_T) k_pre(const int* __restrict__ rows,
                                               const int* __restrict__ cols,
                                               const float* __restrict__ vals,
                                               int2* __restrict__ stg,
                                               int* __restrict__ pcnt,
                                               const float* __restrict__ ue,
                                               const float* __restrict__ ie,
                                               half_t* __restrict__ x0h) {
    __shared__ int lcnt[NB];
    __shared__ int lbase[NB];
    __shared__ int gbase[NB];
    __shared__ int2 lrec[BIN_CHUNK];            // 32 KB
    __shared__ unsigned char lbkt[BIN_CHUNK];   // 4 KB
    int tid = threadIdx.x;
    if (blockIdx.x >= BGRID) {
        // ---- dropout-init: 8 contiguous elems/thread ----
        int j8 = (blockIdx.x - BGRID) * BIN_T + tid;
        if (j8 >= XN / 8) return;
        int j0 = j8 * 8;
        // NUD % 8 == 0 -> chunk never straddles the ue/ie boundary.
        const float* src = (j0 < NUD) ? (ue + j0) : (ie + (j0 - NUD));
        float4 f0 = *(const float4*)(src);
        float4 f1 = *(const float4*)(src + 4);
        float f[8] = {f0.x, f0.y, f0.z, f0.w, f1.x, f1.y, f1.z, f1.w};
        half8 st;
        #pragma unroll
        for (int k = 0; k < 8; ++k) {
            unsigned o0, o1;
            threefry2x32(0u, 42u, 0u, (unsigned)(j0 + k), o0, o1);
            unsigned bits = o0 ^ o1;
            float u = __uint_as_float((bits >> 9) | 0x3f800000u) - 1.0f;
            st[k] = (half_t)((u < 0.8f) ? f[k] * 1.25f : 0.0f);
        }
        *(half8*)(x0h + j0) = st;
        return;
    }
    // ---- bin body ----
    for (int i = tid; i < NB; i += BIN_T) lcnt[i] = 0;
    __syncthreads();
    int base = blockIdx.x * BIN_CHUNK;
    int nv = min(BIN_CHUNK, E - base);          // valid edges in this block
    int lp[BIN_U];          // (bucket<<13) | loff, or -1 for tail
    int2 rec[BIN_U];
    int4  r4[4], c4[4];
    float4 v4[4];
    #pragma unroll
    for (int u4 = 0; u4 < 4; ++u4) {
        int e0 = base + (u4 * BIN_T + tid) * 4;   // E%4==0: all-in or all-out
        if (e0 < E) {
            r4[u4] = *(const int4*)(rows + e0);
            c4[u4] = *(const int4*)(cols + e0);
            v4[u4] = *(const float4*)(vals + e0);
        }
    }
    #pragma unroll
    for (int u4 = 0; u4 < 4; ++u4) {
        int e0 = base + (u4 * BIN_T + tid) * 4;
        int rr[4] = {r4[u4].x, r4[u4].y, r4[u4].z, r4[u4].w};
        int cc[4] = {c4[u4].x, c4[u4].y, c4[u4].z, c4[u4].w};
        float vv[4] = {v4[u4].x, v4[u4].y, v4[u4].z, v4[u4].w};
        #pragma unroll
        for (int k = 0; k < 4; ++k) {
            int u = u4 * 4 + k;
            if (e0 < E) {
                unsigned q = min(__float2int_rn(vv[k] * 65536.f), 16383);
                int b = rr[k] >> 10;
                int loff = atomicAdd(&lcnt[b], 1);
                lp[u] = (b << 13) | loff;           // loff < 4096 < 8192
                rec[u] = make_int2((int)((q << 18) | (unsigned)cc[k]), rr[k]);
            } else {
                lp[u] = -1;
            }
        }
    }
    __syncthreads();
    // Exclusive scan lcnt -> lbase (wave 0), and global base atomics (all).
    if (tid < 64) {
        int carry = 0;
        for (int bb = 0; bb < NB; bb += 64) {
            int i = bb + tid;
            int v = (i < NB) ? lcnt[i] : 0;
            int x = v;
            #pragma unroll
            for (int d = 1; d < 64; d <<= 1) {
                int y = __shfl_up(x, d);
                if (tid >= d) x += y;
            }
            if (i < NB) lbase[i] = carry + x - v;
            carry += __shfl(x, 63);
        }
    }
    for (int i = tid; i < NB; i += BIN_T)
        gbase[i] = atomicAdd(&pcnt[i * 16], lcnt[i]);   // 64B-padded counters
    __syncthreads();
    // Scatter records into the block-local sorted LDS layout.
    #pragma unroll
    for (int u = 0; u < BIN_U; ++u) {
        if (lp[u] >= 0) {
            int b = lp[u] >> 13;
            int j = lbase[b] + (lp[u] & 8191);
            lrec[j] = rec[u];
            lbkt[j] = (unsigned char)b;
        }
    }
    __syncthreads();
    // Coalesced copy-out: consecutive lanes -> consecutive addresses.
    for (int j = tid; j < nv; j += BIN_T) {
        int b = lbkt[j];
        int pos = gbase[b] + (j - lbase[b]);
        if (pos < BPC) stg[(size_t)b * BPC + pos] = lrec[j];
    }
}

// Pure bucket sort: one block per bucket, single pass (records in registers),
// sorted ev built in LDS with bucket-local cursors, streamed out coalesced.
__global__ void __launch_bounds__(1024) k_bsort(const int2* __restrict__ stg,
                                                const int* __restrict__ pcnt,
                                                int* __restrict__ rp,
                                                unsigned* __restrict__ ev) {
    __shared__ int cnt[1024];
    __shared__ int wsum[16];
    __shared__ int sbb;
    __shared__ unsigned sev[BPC];    // 96 KB sorted-ev staging
    int t = threadIdx.x;
    int b = blockIdx.x;
    cnt[t] = 0;
    if (t < 64) {
        // exclusive prefix over buckets < b (one wave, <=3 values/lane)
        int a = 0;
        for (int i = t; i < b; i += 64) a += pcnt[i * 16];
        #pragma unroll
        for (int d = 1; d < 64; d <<= 1) a += __shfl_xor(a, d);
        if (t == 0) sbb = a;
    }
    if (b == 0 && t == 0) rp[NN] = E;    // sentinel
    __syncthreads();
    int tot = min(pcnt[b * 16], BPC);
    int bb = sbb;
    const int2* s = stg + (size_t)b * BPC;
    // Batched register load of this thread's records (independent loads).
    int2 rec[RPT];
    #pragma unroll
    for (int u = 0; u < RPT; ++u) {
        int i = t + u * 1024;
        if (i < tot) rec[u] = s[i];
    }
    #pragma unroll
    for (int u = 0; u < RPT; ++u) {
        int i = t + u * 1024;
        if (i < tot) atomicAdd(&cnt[rec[u].y & 1023], 1);
    }
    __syncthreads();
    // Block-wide exclusive scan of cnt[1024].
    int v = cnt[t];
    int lane = t & 63, w = t >> 6;
    int x = v;
    #pragma unroll
    for (int d = 1; d < 64; d <<= 1) {
        int y = __shfl_up(x, d);
        if (lane >= d) x += y;
    }
    if (lane == 63) wsum[w] = x;
    __syncthreads();
    if (w == 0 && lane < 16) {
        int sv = wsum[lane];
        #pragma unroll
        for (int d = 1; d < 16; d <<= 1) {
            int y = __shfl_up(sv, d);
            if (lane >= d) sv += y;
        }
        wsum[lane] = sv;
    }
    __syncthreads();
    int excl = ((w > 0) ? wsum[w - 1] : 0) + x - v;
    int row = (b << 10) + t;
    if (row < NN) rp[row] = bb + excl;
    __syncthreads();
    cnt[t] = excl;                    // bucket-LOCAL scatter cursor (into sev)
    __syncthreads();
    #pragma unroll
    for (int u = 0; u < RPT; ++u) {
        int i = t + u * 1024;
        if (i < tot) {
            int pos = atomicAdd(&cnt[rec[u].y & 1023], 1);
            sev[pos] = (unsigned)rec[u].x;
        }
    }
    __syncthreads();
    // Coalesced stream-out of the sorted bucket segment.
    for (int i = t; i < tot; i += 1024)
        ev[bb + i] = sev[i];
}

// Pull SpMM over exact CSR, fp16 x (R15/R16 version — 52.7us measured floor).
// Wave = 8 adjacent rows; 8-lane group owns a row (lane l = dims [8l,8l+8)).
// 16-edge batch, 2-deep ev prefetch, compiler-scheduled gathers.
// MODE 0: yh = A*xh (fp16 out). MODE 1: out_f32 = (x0h + y1h + xh + A*xh)*0.25.
template <int MODE>
__global__ void __launch_bounds__(256) k_spmm(const int* __restrict__ rp,
                                              const unsigned* __restrict__ ev,
                                              const half_t* __restrict__ xh,
                                              half_t* __restrict__ yh,
                                              const half_t* __restrict__ x0h,
                                              const half_t* __restrict__ y1h,
                                              float* __restrict__ out) {
    int wid  = threadIdx.x >> 6;             // wave in block: 0..3
    int lane = threadIdx.x & 63;
    int g    = lane >> 3;                    // group (row slot) 0..7
    int l    = lane & 7;                     // lane in group: dims [8l, 8l+8)
    int row  = blockIdx.x * 32 + wid * 8 + g;
    if (row >= NN) return;
    const float inv = 1.0f / 65536.0f;
    int s0  = rp[row];
    int cnt = rp[row + 1] - s0;
    float acc[8] = {0.f, 0.f, 0.f, 0.f, 0.f, 0.f, 0.f, 0.f};
    int gl = g << 3;                         // group's base lane
    int pc0 = (l < cnt)     ? (int)ev[s0 + l] : 0;
    int pc1 = (8 + l < cnt) ? (int)ev[s0 + 8 + l] : 0;
    for (int base = 0; base < cnt; base += 16) {
        int n0 = base + 16 + l;
        int n1 = base + 24 + l;
        int pn0 = (n0 < cnt) ? (int)ev[s0 + n0] : 0;   // prefetch next batch
        int pn1 = (n1 < cnt) ? (int)ev[s0 + n1] : 0;
        int pj[16];
        #pragma unroll
        for (int j = 0; j < 8; ++j) {
            pj[j]     = __shfl(pc0, gl | j);
            pj[8 + j] = __shfl(pc1, gl | j);
        }
        half8 xv[16];
        #pragma unroll
        for (int j = 0; j < 16; ++j)
            xv[j] = *(const half8*)(xh + (pj[j] & 0x3FFFF) * 64 + l * 8);  // 16B
        #pragma unroll
        for (int j = 0; j < 16; ++j) {
            float vj = (float)((unsigned)pj[j] >> 18) * inv;
            #pragma unroll
            for (int k = 0; k < 8; ++k)
                acc[k] = fmaf(vj, (float)xv[j][k], acc[k]);
        }
        pc0 = pn0;
        pc1 = pn1;
    }
    int o = row * 64 + l * 8;
    if (MODE == 0) {
        half8 st;
        #pragma unroll
        for (int k = 0; k < 8; ++k) st[k] = (half_t)acc[k];
        *(half8*)(yh + o) = st;
    } else {
        const half8 a0 = *(const half8*)(x0h + o);   // X0 (fp16)
        const half8 a1 = *(const half8*)(y1h + o);   // Y1 (fp16)
        const half8 a2 = *(const half8*)(xh + o);    // Y2 (linear read)
        float r[8];
        #pragma unroll
        for (int k = 0; k < 8; ++k)
            r[k] = ((float)a0[k] + (float)a1[k] + (float)a2[k] + acc[k]) * 0.25f;
        *(float4*)(out + o)     = make_float4(r[0], r[1], r[2], r[3]);
        *(float4*)(out + o + 4) = make_float4(r[4], r[5], r[6], r[7]);
    }
}

extern "C" void kernel_launch(void* const* d_in, const int* in_sizes, int n_in,
                              void* d_out, int out_size, void* d_ws, size_t ws_size,
                              hipStream_t stream) {
    const float* ue   = (const float*)d_in[0];
    const float* ie   = (const float*)d_in[1];
    const int*   rows = (const int*)d_in[2];
    const int*   cols = (const int*)d_in[3];
    const float* vals = (const float*)d_in[4];
    float* out = (float*)d_out;

    // Workspace: X0h [XN fp16 = 19.2MB] | Y1h [19.2MB] | Y2h [19.2MB]
    //   (stg aliases Y1h..Y2h: NB*BPC*8B = 28.2MB < 38.4MB, dead before spmm
    //    layer 1 writes Y1h) | ev [E*4 = 9.6MB] | rp [NN+1] | pcnt [NB*16].
    //   Total ~68 MB.
    half_t*   X0h   = (half_t*)d_ws;
    half_t*   Y1h   = X0h + XN;
    half_t*   Y2h   = Y1h + XN;
    int2*     stg   = (int2*)Y1h;
    unsigned* ev    = (unsigned*)(Y2h + XN);
    int*      rp    = (int*)(ev + E);
    int*      pcnt  = rp + NN + 4;

    (void)hipMemsetAsync(pcnt, 0, NB * 16 * sizeof(int), stream);
    k_pre<<<BGRID + DGRID, BIN_T, 0, stream>>>(rows, cols, vals, stg, pcnt,
                                               ue, ie, X0h);
    k_bsort<<<NB, 1024, 0, stream>>>(stg, pcnt, rp, ev);

    int sgrid = (NN + 31) / 32;   // 32 rows per block (4 waves x 8 rows)
    k_spmm<0><<<sgrid, 256, 0, stream>>>(rp, ev, X0h, Y1h, nullptr, nullptr, nullptr); // Y1=A*X0
    k_spmm<0><<<sgrid, 256, 0, stream>>>(rp, ev, Y1h, Y2h, nullptr, nullptr, nullptr); // Y2=A*Y1
    k_spmm<1><<<sgrid, 256, 0, stream>>>(rp, ev, Y2h, nullptr, X0h, Y1h, out);         // combine
}